// Round 1
// baseline (203.109 us; speedup 1.0000x reference)
//
#include <hip/hip_runtime.h>

#define NEGV  (-1.0e30f)
#define EPSF  (1e-7f)

__device__ __forceinline__ float lse2(float a, float b) {
    float m = fmaxf(a, b);
    return m + __logf(__expf(a - m) + __expf(b - m));
}
__device__ __forceinline__ float lse3(float a, float b, float c) {
    float m = fmaxf(fmaxf(a, b), c);
    return m + __logf(__expf(a - m) + __expf(b - m) + __expf(c - m));
}

// One wave (64 lanes) per batch element.
// Lane i owns states s=2i+1 (label labels[i]) and s=2i+2 (blank).
// State s=0 (blank) is a scalar: a0 += lp_blank each step (replicated on all lanes).
template<int D>
__global__ __launch_bounds__(64, 1)
void ctc_fwd_kernel(const float* __restrict__ y_pred,
                    const int*   __restrict__ labels,
                    const int*   __restrict__ input_length,
                    const int*   __restrict__ label_length,
                    float*       __restrict__ out,
                    int T, int C, int L)
{
    const int b    = blockIdx.x;
    const int lane = threadIdx.x;          // 0..63, L == 64
    const int Tin  = input_length[b];
    const int ll   = label_length[b];

    const int l     = labels[(size_t)b * L + lane];  // 0..C-2 (never blank)
    const int lprev = __shfl_up(l, 1);
    const bool skip = (lane >= 1) && (l != lprev);   // s=2i+1, s>=2 <=> i>=1
    const int  src  = l >> 1;                        // lane holding class l in its float2
    const bool comp = (l & 1);

    // Row layout: lane j holds classes {2j, 2j+1} as one float2. Stride per t = C/2 float2.
    const float2* rowp = (const float2*)(y_pred + (size_t)b * T * C) + lane;
    const int rstride = C / 2;  // 64

    float2 buf[D];
#pragma unroll
    for (int j = 0; j < D; ++j) buf[j] = rowp[(size_t)j * rstride];

    float a0 = NEGV, ao = NEGV, ae = NEGV;

    for (int tb = 0; tb < T; tb += D) {
#pragma unroll
        for (int j = 0; j < D; ++j) {
            float2 y = buf[j];
            int tn = tb + j + D;
            if (tn < T) buf[j] = rowp[(size_t)tn * rstride];   // prefetch, D in flight
            int t = tb + j;
            if (t < Tin) {
                // gather p[labels[lane]] and p[blank] from the distributed row
                float gx   = __shfl(y.x, src);
                float gy   = __shfl(y.y, src);
                float ylab = comp ? gy : gx;
                float yb   = __shfl(y.y, 63);   // class C-1 = blank
                float lpl  = __logf(ylab + EPSF);
                float lpb  = __logf(yb + EPSF);
                if (t == 0) {
                    a0 = lpb;                          // s=0
                    ao = (lane == 0) ? lpl : NEGV;     // s=1
                    ae = NEGV;                         // s>=2
                } else {
                    float ae_p = __shfl_up(ae, 1);     // alpha[2i]   (old)
                    float ao_p = __shfl_up(ao, 1);     // alpha[2i-1] (old)
                    float a2   = (lane == 0) ? a0 : ae_p;
                    float a3   = skip ? ao_p : NEGV;
                    float nao  = lse3(ao, a2, a3) + lpl;   // s=2i+1
                    float nae  = lse2(ae, ao) + lpb;       // s=2i+2 (blank: no skip)
                    a0 += lpb;                             // s=0: only self-transition
                    ao = nao;
                    ae = nae;
                }
            }
        }
    }

    // s_end = 2*ll (even, lane ll-1's ae), s_end-1 = 2*ll-1 (lane ll-1's ao); ll>=16
    if (lane == ll - 1) {
        out[b] = -lse2(ae, ao);
    }
}

extern "C" void kernel_launch(void* const* d_in, const int* in_sizes, int n_in,
                              void* d_out, int out_size, void* d_ws, size_t ws_size,
                              hipStream_t stream) {
    const float* y_pred       = (const float*)d_in[0];
    const int*   labels       = (const int*)d_in[1];
    const int*   input_length = (const int*)d_in[2];
    const int*   label_length = (const int*)d_in[3];
    float*       out          = (float*)d_out;

    const int B = in_sizes[2];          // 256
    const int L = in_sizes[1] / B;      // 64
    const int T = 512;
    const int C = 128;                  // T*C = in_sizes[0]/B = 65536

    ctc_fwd_kernel<16><<<B, 64, 0, stream>>>(y_pred, labels, input_length,
                                             label_length, out, T, C, L);
}